// Round 1
// baseline (1713.754 us; speedup 1.0000x reference)
//
#include <hip/hip_runtime.h>
#include <math.h>

// Problem constants
#define NB   256      // N_EDUS
#define TT   32
#define EE   300
#define HH   100
#define ROWS 8192     // NB*TT
// Padded dims
#define EP   304      // E padded to /16
#define HP   208      // 2H padded to /16
#define NP   832      // 800 gate cols padded to /64

// ---------------- workspace layout (float offsets) ----------------
#define SZ_WE    (8192u*304u)
#define SZ_XW    (8192u*832u)
#define SZ_OUT   (8192u*208u)
#define SZ_ENC   (256u*200u)
#define SZ_WPAD  (3u*832u*304u)
#define SZ_BPAD  (3u*832u)
#define SZ_WHHT  (6u*40000u)
#define SZ_UTAB  (1536u)
#define SZ_UMISS (8u)
#define SZ_CSTK  (25600u)

#define OFF_WE    0u
#define OFF_XW    (OFF_WE + SZ_WE)
#define OFF_OUT0  (OFF_XW + SZ_XW)
#define OFF_ENC   (OFF_OUT0 + SZ_OUT)
#define OFF_WPAD  (OFF_ENC + SZ_ENC)
#define OFF_BPAD  (OFF_WPAD + SZ_WPAD)
#define OFF_WHHT  (OFF_BPAD + SZ_BPAD)
#define OFF_UTAB  (OFF_WHHT + SZ_WHHT)
#define OFF_UMISS (OFF_UTAB + SZ_UTAB)
#define OFF_CSTK  (OFF_UMISS + SZ_UMISS)
#define OFF_OUT1  OFF_WE   // alias: we dead after layer-0 GEMM

__device__ __forceinline__ float sigf(float x) { return 1.0f / (1.0f + expf(-x)); }

// ---------------- prep: pad/transpose weights ----------------
__global__ void prep_kernel(const float* __restrict__ Wih0, const float* __restrict__ b0,
                            const float* __restrict__ Wih12, const float* __restrict__ b12,
                            const float* __restrict__ Whh0, const float* __restrict__ Whh12,
                            float* __restrict__ wpad, float* __restrict__ bpad,
                            float* __restrict__ whht) {
    int idx = blockIdx.x * blockDim.x + threadIdx.x;
    int stride = gridDim.x * blockDim.x;
    // wpad[l][n<832][k<304]
    for (int i = idx; i < 3 * 832 * 304; i += stride) {
        int l = i / (832 * 304); int rem = i % (832 * 304);
        int n = rem / 304, k = rem % 304;
        float v = 0.f;
        if (l == 0) { if (n < 800 && k < 300) v = Wih0[n * 300 + k]; }
        else        { if (n < 800 && k < 200) v = Wih12[(l - 1) * 160000 + n * 200 + k]; }
        wpad[i] = v;
    }
    // bpad[l][n<832]
    for (int i = idx; i < 3 * 832; i += stride) {
        int l = i / 832, n = i % 832;
        float v = 0.f;
        if (n < 800) v = (l == 0) ? b0[n] : b12[(l - 1) * 800 + n];
        bpad[i] = v;
    }
    // whht[l][d][k<100][j<400] = Whh[l][d][j][k]
    for (int i = idx; i < 6 * 40000; i += stride) {
        int ld = i / 40000; int rem = i % 40000;
        int k = rem / 400, j = rem % 400;
        int l = ld / 2, d = ld % 2;
        float v = (l == 0) ? Whh0[d * 40000 + j * 100 + k]
                           : Whh12[(l - 1) * 80000 + d * 40000 + j * 100 + k];
        whht[i] = v;
    }
}

// ---------------- embedding gather (padded to 304 cols) ----------------
__global__ void embed_kernel(const int* __restrict__ tokens, const float* __restrict__ emb,
                             float* __restrict__ we) {
    int row = blockIdx.x;                 // 8192
    int tok = tokens[row];
    const float4* src = (const float4*)(emb + (size_t)tok * 300u);
    float4* dst = (float4*)(we + (size_t)row * 304u);
    int t = threadIdx.x;                  // 128
    if (t < 75)       dst[t] = src[t];
    else if (t == 75) dst[75] = make_float4(0.f, 0.f, 0.f, 0.f);
}

// ---------------- fp32 tiled GEMM: C[8192 x 832] = A[8192 x K] * W[832 x K]^T + bias ----------------
__global__ __launch_bounds__(256, 4) void gemm_kernel(const float* __restrict__ A, int lda,
                                                      const float* __restrict__ W,
                                                      const float* __restrict__ bias,
                                                      float* __restrict__ C, int K) {
    __shared__ float As[16][128];
    __shared__ float Ws[16][64];
    int m0 = blockIdx.x * 128, n0 = blockIdx.y * 64;
    int tid = threadIdx.x;
    int ty = tid / 16, tx = tid % 16;
    float acc[8][4] = {};
    for (int k0 = 0; k0 < K; k0 += 16) {
        {   // stage A 128x16 (transposed in LDS)
            int r = tid / 2, h = tid % 2;
            const float* ap = A + (size_t)(m0 + r) * (size_t)lda + k0 + h * 8;
            float4 a0 = *(const float4*)ap;
            float4 a1 = *(const float4*)(ap + 4);
            As[h * 8 + 0][r] = a0.x; As[h * 8 + 1][r] = a0.y;
            As[h * 8 + 2][r] = a0.z; As[h * 8 + 3][r] = a0.w;
            As[h * 8 + 4][r] = a1.x; As[h * 8 + 5][r] = a1.y;
            As[h * 8 + 6][r] = a1.z; As[h * 8 + 7][r] = a1.w;
        }
        {   // stage W 64x16 (transposed in LDS); wpad stride fixed 304
            int r = tid / 4, q = tid % 4;
            const float* wp = W + (size_t)(n0 + r) * 304u + k0 + q * 4;
            float4 w0 = *(const float4*)wp;
            Ws[q * 4 + 0][r] = w0.x; Ws[q * 4 + 1][r] = w0.y;
            Ws[q * 4 + 2][r] = w0.z; Ws[q * 4 + 3][r] = w0.w;
        }
        __syncthreads();
#pragma unroll
        for (int kk = 0; kk < 16; ++kk) {
            float4 a0 = *(const float4*)&As[kk][ty * 8];
            float4 a1 = *(const float4*)&As[kk][ty * 8 + 4];
            float4 bv = *(const float4*)&Ws[kk][tx * 4];
            float ar[8] = {a0.x, a0.y, a0.z, a0.w, a1.x, a1.y, a1.z, a1.w};
            float br[4] = {bv.x, bv.y, bv.z, bv.w};
#pragma unroll
            for (int r = 0; r < 8; ++r)
#pragma unroll
                for (int c = 0; c < 4; ++c) acc[r][c] += ar[r] * br[c];
        }
        __syncthreads();
    }
    float4 bv = *(const float4*)(bias + n0 + tx * 4);
#pragma unroll
    for (int r = 0; r < 8; ++r) {
        float4 o;
        o.x = acc[r][0] + bv.x; o.y = acc[r][1] + bv.y;
        o.z = acc[r][2] + bv.z; o.w = acc[r][3] + bv.w;
        *(float4*)&C[(size_t)(m0 + ty * 8 + r) * 832u + n0 + tx * 4] = o;
    }
}

// ---------------- LSTM recurrence: 1 WG handles 2 batch elems of one direction ----------------
__global__ __launch_bounds__(512, 2) void recur_kernel(const float* __restrict__ xW,
                                                       const float* __restrict__ whht,
                                                       const int* __restrict__ lengths,
                                                       float* __restrict__ out,   // [8192 x 208]
                                                       float* __restrict__ enc,   // or null
                                                       int layer) {
    __shared__ float h_s[2][100];
    __shared__ float c_s[2][100];
    __shared__ float g_s[2][400];
    int wg = blockIdx.x;          // 256
    int d = wg >> 7;              // direction
    int p = wg & 127;
    int b0 = 2 * p, b1 = 2 * p + 1;
    int tid = threadIdx.x;
    int j = tid;

    float wr[100];
    if (j < 400) {
        const float* wt = whht + (layer * 2 + d) * 40000;
#pragma unroll
        for (int k = 0; k < 100; ++k) wr[k] = wt[k * 400 + j];
    }
    int len0 = lengths[b0], len1 = lengths[b1];
    if (tid < 200) { int e = tid / 100, u = tid % 100; h_s[e][u] = 0.f; c_s[e][u] = 0.f; }
    __syncthreads();

    float eacc = 0.f;
    int t = d ? 31 : 0;
    int tstep = d ? -1 : 1;
    float nxt0 = 0.f, nxt1 = 0.f;
    if (j < 400) {
        nxt0 = xW[(size_t)(b0 * 32 + t) * 832u + d * 400 + j];
        nxt1 = xW[(size_t)(b1 * 32 + t) * 832u + d * 400 + j];
    }
    for (int it = 0; it < 32; ++it) {
        int tcur = t; t += tstep;
        float a0 = nxt0, a1 = nxt1;
        if (j < 400 && it < 31) {   // prefetch next timestep's xW
            nxt0 = xW[(size_t)(b0 * 32 + t) * 832u + d * 400 + j];
            nxt1 = xW[(size_t)(b1 * 32 + t) * 832u + d * 400 + j];
        }
        if (j < 400) {
            float acc0 = a0, acc1 = a1;
            const float4* h04 = (const float4*)h_s[0];
            const float4* h14 = (const float4*)h_s[1];
#pragma unroll
            for (int q = 0; q < 25; ++q) {
                float4 x0 = h04[q], x1 = h14[q];
                acc0 += wr[4*q+0]*x0.x + wr[4*q+1]*x0.y + wr[4*q+2]*x0.z + wr[4*q+3]*x0.w;
                acc1 += wr[4*q+0]*x1.x + wr[4*q+1]*x1.y + wr[4*q+2]*x1.z + wr[4*q+3]*x1.w;
            }
            g_s[0][j] = acc0; g_s[1][j] = acc1;
        }
        __syncthreads();
        if (tid < 200) {
            int e = tid / 100, u = tid % 100;
            float gi = g_s[e][u], gf = g_s[e][100 + u], gg = g_s[e][200 + u], go = g_s[e][300 + u];
            float cold = c_s[e][u], hold = h_s[e][u];
            float cn = sigf(gf) * cold + sigf(gi) * tanhf(gg);
            float hn = sigf(go) * tanhf(cn);
            int len = e ? len1 : len0;
            bool valid = tcur < len;
            float hv = valid ? hn : hold;
            float cv = valid ? cn : cold;
            h_s[e][u] = hv; c_s[e][u] = cv;
            int b = e ? b1 : b0;
            float ov = valid ? hn : 0.f;
            out[(size_t)(b * 32 + tcur) * 208u + d * 100 + u] = ov;
            eacc += ov;
        }
        if (tid >= 200 && tid < 216) {   // zero the 8 pad cols of both rows
            int q = tid - 200; int e = q / 8, z = q % 8;
            int b = e ? b1 : b0;
            out[(size_t)(b * 32 + tcur) * 208u + 200 + z] = 0.f;
        }
        __syncthreads();
    }
    if (enc != nullptr && tid < 200) {
        int e = tid / 100, u = tid % 100;
        int b = e ? b1 : b0; int len = e ? len1 : len0;
        enc[b * 200 + d * 100 + u] = eacc / (float)len;
    }
}

// ---------------- parser score-contribution tables ----------------
__global__ void utab_kernel(const float* __restrict__ enc, const float* __restrict__ missing,
                            const float* __restrict__ Wa,
                            float* __restrict__ utab, float* __restrict__ umiss) {
    int i = blockIdx.x;           // 0..256 (256 == missing)
    int lane = threadIdx.x;       // 64
    const float* v = (i < 256) ? (enc + i * 200) : missing;
#pragma unroll
    for (int dcase = 0; dcase < 6; ++dcase) {
        int a = dcase & 1, off = (dcase >> 1) * 200;
        float p = 0.f;
        for (int k = lane; k < 200; k += 64) p += Wa[a * 600 + off + k] * v[k];
#pragma unroll
        for (int sh = 32; sh > 0; sh >>= 1) p += __shfl_down(p, sh, 64);
        if (lane == 0) {
            if (i < 256) utab[i * 6 + dcase] = p;
            else         umiss[dcase] = p;
        }
    }
}

// ---------------- sequential shift-reduce parser: single workgroup, 1024 threads ----------------
// Tree-LSTM weights register-resident: thread t<500 owns Wt[t][0:100] (+bias),
// thread 512<=t<1012 owns Wt[t-512][100:200]. 100 VGPRs each -> fits the 128-VGPR
// cap of a 16-wave block (4 waves/SIMD). Eliminates the 400 KB/step scratch-spill
// reload of the previous 512-thread version (wt[200] could not fit 128 VGPRs).
// LDS layout (floats): hstack 25600 | ust 1024 | utab 1536 | umiss 8 | wa 1200 | gates 512 | cbuf 256 | ctag(int) 256 | gp 500
#define P_HSTACK 0
#define P_UST    25600
#define P_UTAB   26624
#define P_UMISS  28160
#define P_WA     28168
#define P_GATES  29368
#define P_CBUF   29880
#define P_CTAG   30136
#define P_GP     30392
#define PARSER_LDS_WORDS 30896
#define PARSER_LDS_BYTES (PARSER_LDS_WORDS * 4)

__global__ __launch_bounds__(1024, 4) void parser_kernel(const float* __restrict__ enc,
                                                         const float* __restrict__ missing,
                                                         const float* __restrict__ Wa,
                                                         const float* __restrict__ ba,
                                                         const float* __restrict__ Wt,
                                                         const float* __restrict__ bt,
                                                         const float* __restrict__ utab_g,
                                                         const float* __restrict__ umiss_g,
                                                         float* __restrict__ cstk,
                                                         float* __restrict__ outp) {
    extern __shared__ float lds[];
    float* S_h     = lds + P_HSTACK;   // [256][100]
    float* S_ust   = lds + P_UST;      // [256][4] : uL0 uL1 uM0 uM1
    float* S_utab  = lds + P_UTAB;     // [256][6]
    float* S_umiss = lds + P_UMISS;    // [6]
    float* S_wa    = lds + P_WA;       // [2][600]
    float* S_g     = lds + P_GATES;    // [500] first-half partial (+bias)
    float* S_cbuf  = lds + P_CBUF;     // [200]
    int*   S_ctag  = (int*)(lds + P_CTAG); // [256]
    float* S_gp    = lds + P_GP;       // [500] second-half partial

    int tid = threadIdx.x;

    // Weight half-row ownership (100 VGPRs per thread, no spill)
    int wrow = -1, wcol = 0;
    if (tid < 500)                      { wrow = tid;       wcol = 0;   }
    else if (tid >= 512 && tid < 1012)  { wrow = tid - 512; wcol = 100; }
    float wt[100];
    if (wrow >= 0) {
        const float* wp = Wt + wrow * 200 + wcol;
#pragma unroll
        for (int k = 0; k < 100; ++k) wt[k] = wp[k];
    }
    float btj = (wrow >= 0 && wcol == 0) ? bt[wrow] : 0.f;
    float ba0 = ba[0], ba1 = ba[1];

    for (int i = tid; i < 1536; i += 1024) S_utab[i] = utab_g[i];
    if (tid < 6) S_umiss[tid] = umiss_g[tid];
    for (int i = tid; i < 1200; i += 1024) S_wa[i] = Wa[i];
    __syncthreads();

    int sp = 0, bp = 0;
    const float NEG = -1e30f;

    for (int step = 0; step < 2 * NB - 1; ++step) {
        // ---- decision (uniform; all threads compute identically from LDS broadcasts) ----
        float uL0, uL1, uM0, uM1, uB0, uB1;
        if (sp >= 2) { int s = sp - 2; uL0 = S_ust[s*4+0]; uL1 = S_ust[s*4+1]; }
        else         { uL0 = S_umiss[0]; uL1 = S_umiss[1]; }
        if (sp >= 1) { int s = sp - 1; uM0 = S_ust[s*4+2]; uM1 = S_ust[s*4+3]; }
        else         { uM0 = S_umiss[2]; uM1 = S_umiss[3]; }
        if (bp < NB) { uB0 = S_utab[bp*6+4]; uB1 = S_utab[bp*6+5]; }
        else         { uB0 = S_umiss[4]; uB1 = S_umiss[5]; }
        float s_sh = uL0 + uM0 + uB0 + ba0;
        float s_rd = uL1 + uM1 + uB1 + ba1;
        float v_sh = (bp < NB) ? s_sh : NEG;
        float v_rd = (sp >= 2) ? s_rd : NEG;
        bool is_shift = !(v_rd > v_sh);

        if (is_shift) {
            int slot = sp < 255 ? sp : 255;
            if (bp < NB) {
                if (tid < 25) {
                    float4 v = ((const float4*)(enc + bp * 200))[tid];
                    *(float4*)&S_h[slot * 100 + tid * 4] = v;
                }
                if (tid < 4) S_ust[slot * 4 + tid] = S_utab[bp * 6 + tid];
                if (tid == 0) S_ctag[slot] = bp;
            } else {
                if (tid < 25) {
                    float4 v = ((const float4*)missing)[tid];
                    *(float4*)&S_h[slot * 100 + tid * 4] = v;
                }
                if (tid < 4) S_ust[slot * 4 + tid] = S_umiss[tid];
                if (tid == 0) S_ctag[slot] = -2;
            }
            sp += 1; bp += 1;
            __syncthreads();
        } else {
            int i1 = sp - 2, i0 = sp - 1;   // reduce implies sp>=2
            // prefetch c-halves (latency hidden under GEMV)
            float cpre = 0.f;
            if (tid < 200) {
                int e = tid / 100, u = tid % 100;
                int slot = e ? i0 : i1;
                int tg = S_ctag[slot];
                const float* p = (tg >= 0) ? (enc + tg * 200 + 100)
                               : ((tg == -1) ? (cstk + slot * 100) : (missing + 100));
                cpre = p[u];
            }
            // tree-LSTM GEMV, split by half-row:
            //   group A (tid<500):      bt[j] + Wt[j][0:100].h(s1)  -> S_g
            //   group B (512<=tid<1012):        Wt[j][100:200].h(s0) -> S_gp
            if (wrow >= 0) {
                const float4* f = (const float4*)&S_h[(wcol ? i0 : i1) * 100];
                float acc0 = wcol ? 0.f : btj;
                float acc1 = 0.f;
#pragma unroll
                for (int q = 0; q < 24; q += 2) {
                    float4 a = f[q];
                    float4 b = f[q + 1];
                    acc0 += wt[4*q+0]*a.x + wt[4*q+1]*a.y + wt[4*q+2]*a.z + wt[4*q+3]*a.w;
                    acc1 += wt[4*q+4]*b.x + wt[4*q+5]*b.y + wt[4*q+6]*b.z + wt[4*q+7]*b.w;
                }
                {
                    float4 a = f[24];
                    acc0 += wt[96]*a.x + wt[97]*a.y + wt[98]*a.z + wt[99]*a.w;
                }
                float acc = acc0 + acc1;
                if (wcol) S_gp[wrow] = acc; else S_g[wrow] = acc;
            }
            if (tid < 200) S_cbuf[tid] = cpre;
            __syncthreads();
            // combine: c = sig(f1)c1 + sig(f2)c2 + sig(i)tanh(u); h = sig(o)tanh(c)
            if (tid < 100) {
                float gi  = S_g[tid]     + S_gp[tid];
                float gf1 = S_g[100+tid] + S_gp[100+tid];
                float gf2 = S_g[200+tid] + S_gp[200+tid];
                float go  = S_g[300+tid] + S_gp[300+tid];
                float gu  = S_g[400+tid] + S_gp[400+tid];
                float c1 = S_cbuf[tid], c2 = S_cbuf[100+tid];
                float c = sigf(gf1)*c1 + sigf(gf2)*c2 + sigf(gi)*tanhf(gu);
                float h = sigf(go)*tanhf(c);
                S_h[i1 * 100 + tid] = h;
                cstk[i1 * 100 + tid] = c;
                S_cbuf[tid] = c;
            }
            if (tid == 0) S_ctag[i1] = -1;
            __syncthreads();
            // score contributions of merged entry: 4 wave-reduced dots of 200
            if (tid < 256) {
                int w = tid >> 6, l = tid & 63;
                int a = w & 1, off = (w >> 1) * 200;
                float p = 0.f;
                for (int k = l; k < 200; k += 64) {
                    float mv = (k < 100) ? S_h[i1 * 100 + k] : S_cbuf[k - 100];
                    p += S_wa[a * 600 + off + k] * mv;
                }
#pragma unroll
                for (int sh = 32; sh > 0; sh >>= 1) p += __shfl_down(p, sh, 64);
                if (l == 0) S_ust[i1 * 4 + w] = p;
            }
            sp -= 1;
            __syncthreads();
        }
    }
    // output stack[0] = [h(100), c(100)]
    if (tid < 100) outp[tid] = S_h[tid];
    if (tid >= 100 && tid < 200) {
        int u = tid - 100;
        int tg = S_ctag[0];
        const float* p = (tg >= 0) ? (enc + tg * 200 + 100)
                       : ((tg == -1) ? cstk : (missing + 100));
        outp[100 + u] = p[u];
    }
}

// ---------------- launch ----------------
extern "C" void kernel_launch(void* const* d_in, const int* in_sizes, int n_in,
                              void* d_out, int out_size, void* d_ws, size_t ws_size,
                              hipStream_t stream) {
    const int*   tokens  = (const int*)d_in[0];
    const int*   lengths = (const int*)d_in[1];
    const float* emb     = (const float*)d_in[2];
    const float* Wih0    = (const float*)d_in[3];
    const float* Whh0    = (const float*)d_in[4];
    const float* b0      = (const float*)d_in[5];
    const float* Wih12   = (const float*)d_in[6];
    const float* Whh12   = (const float*)d_in[7];
    const float* b12     = (const float*)d_in[8];
    const float* missing = (const float*)d_in[9];
    const float* Wa      = (const float*)d_in[10];
    const float* ba      = (const float*)d_in[11];
    const float* Wt      = (const float*)d_in[12];
    const float* bt      = (const float*)d_in[13];

    float* ws_f  = (float*)d_ws;
    float* we    = ws_f + OFF_WE;
    float* xw    = ws_f + OFF_XW;
    float* out0  = ws_f + OFF_OUT0;
    float* out1  = ws_f + OFF_OUT1;   // aliases `we` (dead by then)
    float* enc   = ws_f + OFF_ENC;
    float* wpad  = ws_f + OFF_WPAD;
    float* bpad  = ws_f + OFF_BPAD;
    float* whht  = ws_f + OFF_WHHT;
    float* utab  = ws_f + OFF_UTAB;
    float* umiss = ws_f + OFF_UMISS;
    float* cstk  = ws_f + OFF_CSTK;
    float* outp  = (float*)d_out;

    (void)hipFuncSetAttribute((const void*)parser_kernel,
                              hipFuncAttributeMaxDynamicSharedMemorySize, PARSER_LDS_BYTES);

    prep_kernel<<<1024, 256, 0, stream>>>(Wih0, b0, Wih12, b12, Whh0, Whh12, wpad, bpad, whht);
    embed_kernel<<<8192, 128, 0, stream>>>(tokens, emb, we);

    // layer 0
    gemm_kernel<<<dim3(64, 13), 256, 0, stream>>>(we, EP, wpad + 0 * 832 * 304, bpad + 0 * 832, xw, 304);
    recur_kernel<<<256, 512, 0, stream>>>(xw, whht, lengths, out0, nullptr, 0);
    // layer 1
    gemm_kernel<<<dim3(64, 13), 256, 0, stream>>>(out0, HP, wpad + 1 * 832 * 304, bpad + 1 * 832, xw, 208);
    recur_kernel<<<256, 512, 0, stream>>>(xw, whht, lengths, out1, nullptr, 1);
    // layer 2 (writes enc; seq output goes to dead out0)
    gemm_kernel<<<dim3(64, 13), 256, 0, stream>>>(out1, HP, wpad + 2 * 832 * 304, bpad + 2 * 832, xw, 208);
    recur_kernel<<<256, 512, 0, stream>>>(xw, whht, lengths, out0, enc, 2);

    utab_kernel<<<257, 64, 0, stream>>>(enc, missing, Wa, utab, umiss);
    parser_kernel<<<1, 1024, PARSER_LDS_BYTES, stream>>>(enc, missing, Wa, ba, Wt, bt,
                                                         utab, umiss, cstk, outp);
}

// Round 3
// 1547.709 us; speedup vs baseline: 1.1073x; 1.1073x over previous
//
#include <hip/hip_runtime.h>
#include <math.h>

// Problem constants
#define NB   256      // N_EDUS
#define TT   32
#define EE   300
#define HH   100
#define ROWS 8192     // NB*TT
// Padded dims
#define EP   304      // E padded to /16
#define HP   208      // 2H padded to /16
#define NP   832      // 800 gate cols padded to /64

// ---------------- workspace layout (float offsets) ----------------
#define SZ_WE    (8192u*304u)
#define SZ_XW    (8192u*832u)
#define SZ_OUT   (8192u*208u)
#define SZ_ENC   (256u*200u)
#define SZ_WPAD  (3u*832u*304u)
#define SZ_BPAD  (3u*832u)
#define SZ_WHHT  (6u*40000u)
#define SZ_UTAB  (1536u)
#define SZ_UMISS (8u)
#define SZ_CSTK  (25600u)

#define OFF_WE    0u
#define OFF_XW    (OFF_WE + SZ_WE)
#define OFF_OUT0  (OFF_XW + SZ_XW)
#define OFF_ENC   (OFF_OUT0 + SZ_OUT)
#define OFF_WPAD  (OFF_ENC + SZ_ENC)
#define OFF_BPAD  (OFF_WPAD + SZ_WPAD)
#define OFF_WHHT  (OFF_BPAD + SZ_BPAD)
#define OFF_UTAB  (OFF_WHHT + SZ_WHHT)
#define OFF_UMISS (OFF_UTAB + SZ_UTAB)
#define OFF_CSTK  (OFF_UMISS + SZ_UMISS)
#define OFF_OUT1  OFF_WE   // alias: we dead after layer-0 GEMM

__device__ __forceinline__ float sigf(float x) { return 1.0f / (1.0f + expf(-x)); }

// ---------------- prep: pad/transpose weights ----------------
__global__ void prep_kernel(const float* __restrict__ Wih0, const float* __restrict__ b0,
                            const float* __restrict__ Wih12, const float* __restrict__ b12,
                            const float* __restrict__ Whh0, const float* __restrict__ Whh12,
                            float* __restrict__ wpad, float* __restrict__ bpad,
                            float* __restrict__ whht) {
    int idx = blockIdx.x * blockDim.x + threadIdx.x;
    int stride = gridDim.x * blockDim.x;
    // wpad[l][n<832][k<304]
    for (int i = idx; i < 3 * 832 * 304; i += stride) {
        int l = i / (832 * 304); int rem = i % (832 * 304);
        int n = rem / 304, k = rem % 304;
        float v = 0.f;
        if (l == 0) { if (n < 800 && k < 300) v = Wih0[n * 300 + k]; }
        else        { if (n < 800 && k < 200) v = Wih12[(l - 1) * 160000 + n * 200 + k]; }
        wpad[i] = v;
    }
    // bpad[l][n<832]
    for (int i = idx; i < 3 * 832; i += stride) {
        int l = i / 832, n = i % 832;
        float v = 0.f;
        if (n < 800) v = (l == 0) ? b0[n] : b12[(l - 1) * 800 + n];
        bpad[i] = v;
    }
    // whht[l][d][k<100][j<400] = Whh[l][d][j][k]
    for (int i = idx; i < 6 * 40000; i += stride) {
        int ld = i / 40000; int rem = i % 40000;
        int k = rem / 400, j = rem % 400;
        int l = ld / 2, d = ld % 2;
        float v = (l == 0) ? Whh0[d * 40000 + j * 100 + k]
                           : Whh12[(l - 1) * 80000 + d * 40000 + j * 100 + k];
        whht[i] = v;
    }
}

// ---------------- embedding gather (padded to 304 cols) ----------------
__global__ void embed_kernel(const int* __restrict__ tokens, const float* __restrict__ emb,
                             float* __restrict__ we) {
    int row = blockIdx.x;                 // 8192
    int tok = tokens[row];
    const float4* src = (const float4*)(emb + (size_t)tok * 300u);
    float4* dst = (float4*)(we + (size_t)row * 304u);
    int t = threadIdx.x;                  // 128
    if (t < 75)       dst[t] = src[t];
    else if (t == 75) dst[75] = make_float4(0.f, 0.f, 0.f, 0.f);
}

// ---------------- fp32 tiled GEMM: C[8192 x 832] = A[8192 x K] * W[832 x K]^T + bias ----------------
__global__ __launch_bounds__(256, 4) void gemm_kernel(const float* __restrict__ A, int lda,
                                                      const float* __restrict__ W,
                                                      const float* __restrict__ bias,
                                                      float* __restrict__ C, int K) {
    __shared__ float As[16][128];
    __shared__ float Ws[16][64];
    int m0 = blockIdx.x * 128, n0 = blockIdx.y * 64;
    int tid = threadIdx.x;
    int ty = tid / 16, tx = tid % 16;
    float acc[8][4] = {};
    for (int k0 = 0; k0 < K; k0 += 16) {
        {   // stage A 128x16 (transposed in LDS)
            int r = tid / 2, h = tid % 2;
            const float* ap = A + (size_t)(m0 + r) * (size_t)lda + k0 + h * 8;
            float4 a0 = *(const float4*)ap;
            float4 a1 = *(const float4*)(ap + 4);
            As[h * 8 + 0][r] = a0.x; As[h * 8 + 1][r] = a0.y;
            As[h * 8 + 2][r] = a0.z; As[h * 8 + 3][r] = a0.w;
            As[h * 8 + 4][r] = a1.x; As[h * 8 + 5][r] = a1.y;
            As[h * 8 + 6][r] = a1.z; As[h * 8 + 7][r] = a1.w;
        }
        {   // stage W 64x16 (transposed in LDS); wpad stride fixed 304
            int r = tid / 4, q = tid % 4;
            const float* wp = W + (size_t)(n0 + r) * 304u + k0 + q * 4;
            float4 w0 = *(const float4*)wp;
            Ws[q * 4 + 0][r] = w0.x; Ws[q * 4 + 1][r] = w0.y;
            Ws[q * 4 + 2][r] = w0.z; Ws[q * 4 + 3][r] = w0.w;
        }
        __syncthreads();
#pragma unroll
        for (int kk = 0; kk < 16; ++kk) {
            float4 a0 = *(const float4*)&As[kk][ty * 8];
            float4 a1 = *(const float4*)&As[kk][ty * 8 + 4];
            float4 bv = *(const float4*)&Ws[kk][tx * 4];
            float ar[8] = {a0.x, a0.y, a0.z, a0.w, a1.x, a1.y, a1.z, a1.w};
            float br[4] = {bv.x, bv.y, bv.z, bv.w};
#pragma unroll
            for (int r = 0; r < 8; ++r)
#pragma unroll
                for (int c = 0; c < 4; ++c) acc[r][c] += ar[r] * br[c];
        }
        __syncthreads();
    }
    float4 bv = *(const float4*)(bias + n0 + tx * 4);
#pragma unroll
    for (int r = 0; r < 8; ++r) {
        float4 o;
        o.x = acc[r][0] + bv.x; o.y = acc[r][1] + bv.y;
        o.z = acc[r][2] + bv.z; o.w = acc[r][3] + bv.w;
        *(float4*)&C[(size_t)(m0 + ty * 8 + r) * 832u + n0 + tx * 4] = o;
    }
}

// ---------------- LSTM recurrence: 1 WG handles 2 batch elems of one direction ----------------
// __launch_bounds__(512, 1): second arg behaves as min BLOCKS/CU (CUDA-style) on this
// toolchain -> (512,2) capped VGPR budget at 128, borderline for wr[100]. Grid is 256
// = 1 WG/CU anyway, so (512,1) raises the budget to 256 with zero occupancy cost.
__global__ __launch_bounds__(512, 1) void recur_kernel(const float* __restrict__ xW,
                                                       const float* __restrict__ whht,
                                                       const int* __restrict__ lengths,
                                                       float* __restrict__ out,   // [8192 x 208]
                                                       float* __restrict__ enc,   // or null
                                                       int layer) {
    __shared__ float h_s[2][100];
    __shared__ float c_s[2][100];
    __shared__ float g_s[2][400];
    int wg = blockIdx.x;          // 256
    int d = wg >> 7;              // direction
    int p = wg & 127;
    int b0 = 2 * p, b1 = 2 * p + 1;
    int tid = threadIdx.x;
    int j = tid;

    float wr[100];
    if (j < 400) {
        const float* wt = whht + (layer * 2 + d) * 40000;
#pragma unroll
        for (int k = 0; k < 100; ++k) wr[k] = wt[k * 400 + j];
    }
    int len0 = lengths[b0], len1 = lengths[b1];
    if (tid < 200) { int e = tid / 100, u = tid % 100; h_s[e][u] = 0.f; c_s[e][u] = 0.f; }
    __syncthreads();

    float eacc = 0.f;
    int t = d ? 31 : 0;
    int tstep = d ? -1 : 1;
    float nxt0 = 0.f, nxt1 = 0.f;
    if (j < 400) {
        nxt0 = xW[(size_t)(b0 * 32 + t) * 832u + d * 400 + j];
        nxt1 = xW[(size_t)(b1 * 32 + t) * 832u + d * 400 + j];
    }
    for (int it = 0; it < 32; ++it) {
        int tcur = t; t += tstep;
        float a0 = nxt0, a1 = nxt1;
        if (j < 400 && it < 31) {   // prefetch next timestep's xW
            nxt0 = xW[(size_t)(b0 * 32 + t) * 832u + d * 400 + j];
            nxt1 = xW[(size_t)(b1 * 32 + t) * 832u + d * 400 + j];
        }
        if (j < 400) {
            float acc0 = a0, acc1 = a1;
            const float4* h04 = (const float4*)h_s[0];
            const float4* h14 = (const float4*)h_s[1];
#pragma unroll
            for (int q = 0; q < 25; ++q) {
                float4 x0 = h04[q], x1 = h14[q];
                acc0 += wr[4*q+0]*x0.x + wr[4*q+1]*x0.y + wr[4*q+2]*x0.z + wr[4*q+3]*x0.w;
                acc1 += wr[4*q+0]*x1.x + wr[4*q+1]*x1.y + wr[4*q+2]*x1.z + wr[4*q+3]*x1.w;
            }
            g_s[0][j] = acc0; g_s[1][j] = acc1;
        }
        __syncthreads();
        if (tid < 200) {
            int e = tid / 100, u = tid % 100;
            float gi = g_s[e][u], gf = g_s[e][100 + u], gg = g_s[e][200 + u], go = g_s[e][300 + u];
            float cold = c_s[e][u], hold = h_s[e][u];
            float cn = sigf(gf) * cold + sigf(gi) * tanhf(gg);
            float hn = sigf(go) * tanhf(cn);
            int len = e ? len1 : len0;
            bool valid = tcur < len;
            float hv = valid ? hn : hold;
            float cv = valid ? cn : cold;
            h_s[e][u] = hv; c_s[e][u] = cv;
            int b = e ? b1 : b0;
            float ov = valid ? hn : 0.f;
            out[(size_t)(b * 32 + tcur) * 208u + d * 100 + u] = ov;
            eacc += ov;
        }
        if (tid >= 200 && tid < 216) {   // zero the 8 pad cols of both rows
            int q = tid - 200; int e = q / 8, z = q % 8;
            int b = e ? b1 : b0;
            out[(size_t)(b * 32 + tcur) * 208u + 200 + z] = 0.f;
        }
        __syncthreads();
    }
    if (enc != nullptr && tid < 200) {
        int e = tid / 100, u = tid % 100;
        int b = e ? b1 : b0; int len = e ? len1 : len0;
        enc[b * 200 + d * 100 + u] = eacc / (float)len;
    }
}

// ---------------- parser score-contribution tables ----------------
__global__ void utab_kernel(const float* __restrict__ enc, const float* __restrict__ missing,
                            const float* __restrict__ Wa,
                            float* __restrict__ utab, float* __restrict__ umiss) {
    int i = blockIdx.x;           // 0..256 (256 == missing)
    int lane = threadIdx.x;       // 64
    const float* v = (i < 256) ? (enc + i * 200) : missing;
#pragma unroll
    for (int dcase = 0; dcase < 6; ++dcase) {
        int a = dcase & 1, off = (dcase >> 1) * 200;
        float p = 0.f;
        for (int k = lane; k < 200; k += 64) p += Wa[a * 600 + off + k] * v[k];
#pragma unroll
        for (int sh = 32; sh > 0; sh >>= 1) p += __shfl_down(p, sh, 64);
        if (lane == 0) {
            if (i < 256) utab[i * 6 + dcase] = p;
            else         umiss[dcase] = p;
        }
    }
}

// ---------------- sequential shift-reduce parser: single workgroup, 512 threads ----------------
// __launch_bounds__(512, 1): on this toolchain the 2nd arg acts as min BLOCKS/CU
// (evidence: (512,2) -> VGPR_Count exactly 128; (1024,4) -> exactly 64 -- both equal
// the implied budget, with wt[] spilled to scratch and ~400 KB/step L2 reload as the
// dominant parser cost). With 1 block/CU the budget is 256 VGPRs: wt[200] (+~30 temps)
// becomes register-resident, eliminating the scratch stream. Grid is 1 WG regardless.
// LDS layout (floats): hstack 25600 | ust 1024 | utab 1536 | umiss 8 | wa 1200 | gates 512 | cbuf 256 | ctag(int) 256
#define P_HSTACK 0
#define P_UST    25600
#define P_UTAB   26624
#define P_UMISS  28160
#define P_WA     28168
#define P_GATES  29368
#define P_CBUF   29880
#define P_CTAG   30136
#define PARSER_LDS_WORDS 30392
#define PARSER_LDS_BYTES (PARSER_LDS_WORDS * 4)

__global__ __launch_bounds__(512, 1) void parser_kernel(const float* __restrict__ enc,
                                                        const float* __restrict__ missing,
                                                        const float* __restrict__ Wa,
                                                        const float* __restrict__ ba,
                                                        const float* __restrict__ Wt,
                                                        const float* __restrict__ bt,
                                                        const float* __restrict__ utab_g,
                                                        const float* __restrict__ umiss_g,
                                                        float* __restrict__ cstk,
                                                        float* __restrict__ outp) {
    extern __shared__ float lds[];
    float* S_h     = lds + P_HSTACK;   // [256][100]
    float* S_ust   = lds + P_UST;      // [256][4] : uL0 uL1 uM0 uM1
    float* S_utab  = lds + P_UTAB;     // [256][6]
    float* S_umiss = lds + P_UMISS;    // [6]
    float* S_wa    = lds + P_WA;       // [2][600]
    float* S_g     = lds + P_GATES;    // [500]
    float* S_cbuf  = lds + P_CBUF;     // [200]
    int*   S_ctag  = (int*)(lds + P_CTAG); // [256]

    int tid = threadIdx.x;

    // Wt rows into registers: thread j owns Wt[j][0..199]
    float wt[200];
    if (tid < 500) {
#pragma unroll
        for (int k = 0; k < 200; ++k) wt[k] = Wt[tid * 200 + k];
    }
    float btj = (tid < 500) ? bt[tid] : 0.f;
    float ba0 = ba[0], ba1 = ba[1];

    for (int i = tid; i < 1536; i += 512) S_utab[i] = utab_g[i];
    if (tid < 6) S_umiss[tid] = umiss_g[tid];
    for (int i = tid; i < 1200; i += 512) S_wa[i] = Wa[i];
    __syncthreads();

    int sp = 0, bp = 0;
    const float NEG = -1e30f;

    for (int step = 0; step < 2 * NB - 1; ++step) {
        // ---- decision (uniform; all threads compute identically from LDS broadcasts) ----
        float uL0, uL1, uM0, uM1, uB0, uB1;
        if (sp >= 2) { int s = sp - 2; uL0 = S_ust[s*4+0]; uL1 = S_ust[s*4+1]; }
        else         { uL0 = S_umiss[0]; uL1 = S_umiss[1]; }
        if (sp >= 1) { int s = sp - 1; uM0 = S_ust[s*4+2]; uM1 = S_ust[s*4+3]; }
        else         { uM0 = S_umiss[2]; uM1 = S_umiss[3]; }
        if (bp < NB) { uB0 = S_utab[bp*6+4]; uB1 = S_utab[bp*6+5]; }
        else         { uB0 = S_umiss[4]; uB1 = S_umiss[5]; }
        float s_sh = uL0 + uM0 + uB0 + ba0;
        float s_rd = uL1 + uM1 + uB1 + ba1;
        float v_sh = (bp < NB) ? s_sh : NEG;
        float v_rd = (sp >= 2) ? s_rd : NEG;
        bool is_shift = !(v_rd > v_sh);

        if (is_shift) {
            int slot = sp < 255 ? sp : 255;
            if (bp < NB) {
                if (tid < 25) {
                    float4 v = ((const float4*)(enc + bp * 200))[tid];
                    *(float4*)&S_h[slot * 100 + tid * 4] = v;
                }
                if (tid < 4) S_ust[slot * 4 + tid] = S_utab[bp * 6 + tid];
                if (tid == 0) S_ctag[slot] = bp;
            } else {
                if (tid < 25) {
                    float4 v = ((const float4*)missing)[tid];
                    *(float4*)&S_h[slot * 100 + tid * 4] = v;
                }
                if (tid < 4) S_ust[slot * 4 + tid] = S_umiss[tid];
                if (tid == 0) S_ctag[slot] = -2;
            }
            sp += 1; bp += 1;
            __syncthreads();
        } else {
            int i1 = sp - 2, i0 = sp - 1;   // reduce implies sp>=2
            // prefetch c-halves (latency hidden under GEMV)
            float cpre = 0.f;
            if (tid < 200) {
                int e = tid / 100, u = tid % 100;
                int slot = e ? i0 : i1;
                int tg = S_ctag[slot];
                const float* p = (tg >= 0) ? (enc + tg * 200 + 100)
                               : ((tg == -1) ? (cstk + slot * 100) : (missing + 100));
                cpre = p[u];
            }
            // tree-LSTM GEMV: gates[j] = bt[j] + Wt[j][0:100].h(s1) + Wt[j][100:200].h(s0)
            if (tid < 500) {
                float acc = btj;
                const float4* f1 = (const float4*)&S_h[i1 * 100];
                const float4* f0 = (const float4*)&S_h[i0 * 100];
#pragma unroll
                for (int q = 0; q < 25; ++q) {
                    float4 a = f1[q];
                    acc += wt[4*q+0]*a.x + wt[4*q+1]*a.y + wt[4*q+2]*a.z + wt[4*q+3]*a.w;
                }
#pragma unroll
                for (int q = 0; q < 25; ++q) {
                    float4 a = f0[q];
                    acc += wt[100+4*q+0]*a.x + wt[100+4*q+1]*a.y + wt[100+4*q+2]*a.z + wt[100+4*q+3]*a.w;
                }
                S_g[tid] = acc;
            }
            if (tid < 200) S_cbuf[tid] = cpre;
            __syncthreads();
            // combine: c = sig(f1)c1 + sig(f2)c2 + sig(i)tanh(u); h = sig(o)tanh(c)
            if (tid < 100) {
                float gi = S_g[tid], gf1 = S_g[100+tid], gf2 = S_g[200+tid];
                float go = S_g[300+tid], gu = S_g[400+tid];
                float c1 = S_cbuf[tid], c2 = S_cbuf[100+tid];
                float c = sigf(gf1)*c1 + sigf(gf2)*c2 + sigf(gi)*tanhf(gu);
                float h = sigf(go)*tanhf(c);
                S_h[i1 * 100 + tid] = h;
                cstk[i1 * 100 + tid] = c;
                S_cbuf[tid] = c;
            }
            if (tid == 0) S_ctag[i1] = -1;
            __syncthreads();
            // score contributions of merged entry: 4 wave-reduced dots of 200
            if (tid < 256) {
                int w = tid >> 6, l = tid & 63;
                int a = w & 1, off = (w >> 1) * 200;
                float p = 0.f;
                for (int k = l; k < 200; k += 64) {
                    float mv = (k < 100) ? S_h[i1 * 100 + k] : S_cbuf[k - 100];
                    p += S_wa[a * 600 + off + k] * mv;
                }
#pragma unroll
                for (int sh = 32; sh > 0; sh >>= 1) p += __shfl_down(p, sh, 64);
                if (l == 0) S_ust[i1 * 4 + w] = p;
            }
            sp -= 1;
            __syncthreads();
        }
    }
    // output stack[0] = [h(100), c(100)]
    if (tid < 100) outp[tid] = S_h[tid];
    if (tid >= 100 && tid < 200) {
        int u = tid - 100;
        int tg = S_ctag[0];
        const float* p = (tg >= 0) ? (enc + tg * 200 + 100)
                       : ((tg == -1) ? cstk : (missing + 100));
        outp[100 + u] = p[u];
    }
}

// ---------------- launch ----------------
extern "C" void kernel_launch(void* const* d_in, const int* in_sizes, int n_in,
                              void* d_out, int out_size, void* d_ws, size_t ws_size,
                              hipStream_t stream) {
    const int*   tokens  = (const int*)d_in[0];
    const int*   lengths = (const int*)d_in[1];
    const float* emb     = (const float*)d_in[2];
    const float* Wih0    = (const float*)d_in[3];
    const float* Whh0    = (const float*)d_in[4];
    const float* b0      = (const float*)d_in[5];
    const float* Wih12   = (const float*)d_in[6];
    const float* Whh12   = (const float*)d_in[7];
    const float* b12     = (const float*)d_in[8];
    const float* missing = (const float*)d_in[9];
    const float* Wa      = (const float*)d_in[10];
    const float* ba      = (const float*)d_in[11];
    const float* Wt      = (const float*)d_in[12];
    const float* bt      = (const float*)d_in[13];

    float* ws_f  = (float*)d_ws;
    float* we    = ws_f + OFF_WE;
    float* xw    = ws_f + OFF_XW;
    float* out0  = ws_f + OFF_OUT0;
    float* out1  = ws_f + OFF_OUT1;   // aliases `we` (dead by then)
    float* enc   = ws_f + OFF_ENC;
    float* wpad  = ws_f + OFF_WPAD;
    float* bpad  = ws_f + OFF_BPAD;
    float* whht  = ws_f + OFF_WHHT;
    float* utab  = ws_f + OFF_UTAB;
    float* umiss = ws_f + OFF_UMISS;
    float* cstk  = ws_f + OFF_CSTK;
    float* outp  = (float*)d_out;

    (void)hipFuncSetAttribute((const void*)parser_kernel,
                              hipFuncAttributeMaxDynamicSharedMemorySize, PARSER_LDS_BYTES);

    prep_kernel<<<1024, 256, 0, stream>>>(Wih0, b0, Wih12, b12, Whh0, Whh12, wpad, bpad, whht);
    embed_kernel<<<8192, 128, 0, stream>>>(tokens, emb, we);

    // layer 0
    gemm_kernel<<<dim3(64, 13), 256, 0, stream>>>(we, EP, wpad + 0 * 832 * 304, bpad + 0 * 832, xw, 304);
    recur_kernel<<<256, 512, 0, stream>>>(xw, whht, lengths, out0, nullptr, 0);
    // layer 1
    gemm_kernel<<<dim3(64, 13), 256, 0, stream>>>(out0, HP, wpad + 1 * 832 * 304, bpad + 1 * 832, xw, 208);
    recur_kernel<<<256, 512, 0, stream>>>(xw, whht, lengths, out1, nullptr, 1);
    // layer 2 (writes enc; seq output goes to dead out0)
    gemm_kernel<<<dim3(64, 13), 256, 0, stream>>>(out1, HP, wpad + 2 * 832 * 304, bpad + 2 * 832, xw, 208);
    recur_kernel<<<256, 512, 0, stream>>>(xw, whht, lengths, out0, enc, 2);

    utab_kernel<<<257, 64, 0, stream>>>(enc, missing, Wa, utab, umiss);
    parser_kernel<<<1, 512, PARSER_LDS_BYTES, stream>>>(enc, missing, Wa, ba, Wt, bt,
                                                        utab, umiss, cstk, outp);
}